// Round 1
// baseline (3144.646 us; speedup 1.0000x reference)
//
#include <hip/hip_runtime.h>
#include <math.h>

// Problem constants (from reference setup_inputs)
constexpr int SEQ  = 2048;  // T
constexpr int BATCH = 64;   // B
constexpr int EMB  = 100;   // E
constexpr int HID  = 128;   // H
constexpr int G3   = 384;   // 3*H
constexpr int NS   = 6;     // S (CRF states)
constexpr int BSEL = 63;    // only batch row 63 affects the output

// ---------------------------------------------------------------------------
// Kernel 1: embedding lookup + input projection for batch row 63 only.
// gi_f[t][j] = dot(Wf_ih[j,:], emb[sent[63,t],:]) + bf_ih[j]   (same for bwd)
// grid = SEQ blocks, block = 384 threads (thread j -> output row j)
// ---------------------------------------------------------------------------
__global__ __launch_bounds__(G3) void k_input_proj(
    const int* __restrict__ sent, const float* __restrict__ emb,
    const float* __restrict__ Wf_ih, const float* __restrict__ bf_ih,
    const float* __restrict__ Wb_ih, const float* __restrict__ bb_ih,
    float* __restrict__ gi_f, float* __restrict__ gi_b)
{
    const int t = blockIdx.x;
    const int j = threadIdx.x;            // 0..383
    __shared__ float x_s[EMB];

    const int tok = sent[BSEL * SEQ + t];
    if (j < EMB) x_s[j] = emb[(size_t)tok * EMB + j];
    __syncthreads();

    const float* wf = Wf_ih + (size_t)j * EMB;
    const float* wb = Wb_ih + (size_t)j * EMB;
    float af = 0.f, ab = 0.f;
#pragma unroll 4
    for (int k = 0; k < EMB; ++k) {
        const float xv = x_s[k];
        af += wf[k] * xv;
        ab += wb[k] * xv;
    }
    gi_f[t * G3 + j] = af + bf_ih[j];
    gi_b[t * G3 + j] = ab + bb_ih[j];
}

// ---------------------------------------------------------------------------
// Kernel 2: sequential GRU recurrence, one block per direction.
// 768 threads: 2 threads per output row (each owns 64 Whh weights in VGPRs),
// h lives in LDS, pair-reduce via shfl_xor, gate update by threads 0..127.
// ---------------------------------------------------------------------------
__global__ __launch_bounds__(768, 3) void k_recur(
    const float* __restrict__ gi_f, const float* __restrict__ gi_b,
    const float* __restrict__ Wf_hh, const float* __restrict__ bf_hh,
    const float* __restrict__ Wb_hh, const float* __restrict__ bb_hh,
    const float* __restrict__ h0,
    float* __restrict__ fwd, float* __restrict__ bwd)
{
    const int dir = blockIdx.x;           // 0 = forward, 1 = backward
    const float* gi  = dir ? gi_b  : gi_f;
    const float* Whh = dir ? Wb_hh : Wf_hh;
    const float* bhh = dir ? bb_hh : bf_hh;
    float* outs      = dir ? bwd   : fwd;

    const int tid  = threadIdx.x;         // 0..767
    const int j    = tid >> 1;            // output row 0..383
    const int half = tid & 1;             // which 64-wide k slice

    // Whh row slice -> registers (one-time, ~192KB total per block)
    float w[64];
    const float* wrow = Whh + (size_t)j * HID + half * 64;
#pragma unroll
    for (int k = 0; k < 64; ++k) w[k] = wrow[k];
    const float bj = bhh[j];

    __shared__ float h_lds[HID];          // current hidden state
    __shared__ float Ssum[G3];            // j<256: gi+gh (r,z preact); j>=256: gi_n
    __shared__ float HN[HID];             // gh_n

    if (tid < HID) h_lds[tid] = h0[(size_t)dir * BATCH * HID + BSEL * HID + tid];
    __syncthreads();

    for (int step = 0; step < SEQ; ++step) {
        const int t = dir ? (SEQ - 1 - step) : step;
        const float giv = gi[t * G3 + j];           // issued early, used late

        // dot(Whh[j, half*64 : half*64+64], h)
        const float4* h4 = (const float4*)h_lds;
        float a0 = 0.f, a1 = 0.f, a2 = 0.f, a3 = 0.f;
#pragma unroll
        for (int k4 = 0; k4 < 16; ++k4) {
            const float4 hv = h4[half * 16 + k4];
            a0 += w[k4 * 4 + 0] * hv.x;
            a1 += w[k4 * 4 + 1] * hv.y;
            a2 += w[k4 * 4 + 2] * hv.z;
            a3 += w[k4 * 4 + 3] * hv.w;
        }
        float acc = (a0 + a1) + (a2 + a3);
        acc += __shfl_xor(acc, 1);                  // pair-sum: full 128-dot

        if (half == 0) {
            const float gh = acc + bj;
            if (j < 2 * HID) Ssum[j] = giv + gh;    // r,z pre-activations
            else { Ssum[j] = giv; HN[j - 2 * HID] = gh; }   // gi_n, gh_n
        }
        __syncthreads();   // everyone done reading h_lds and writing Ssum/HN

        if (tid < HID) {
            const int u = tid;
            const float r = 1.f / (1.f + __expf(-Ssum[u]));
            const float z = 1.f / (1.f + __expf(-Ssum[HID + u]));
            const float n = tanhf(Ssum[2 * HID + u] + r * HN[u]);
            const float hn = (1.f - z) * n + z * h_lds[u];
            h_lds[u] = hn;
            outs[(size_t)t * HID + u] = hn;
        }
        __syncthreads();   // h_lds updated before next step's reads
    }
}

// ---------------------------------------------------------------------------
// Kernel 3: output logits + softmax (parallel over t, probs -> LDS),
// then 6-lane shuffle Viterbi forward pass (backpointers -> LDS),
// then single-lane backtrack. One block, 384 threads.
// ---------------------------------------------------------------------------
__global__ __launch_bounds__(G3) void k_out_viterbi(
    const float* __restrict__ fwd, const float* __restrict__ bwd,
    const float* __restrict__ W_out, const float* __restrict__ b_out,
    const float* __restrict__ trans, float* __restrict__ out)
{
    __shared__ float p_lds[SEQ * NS];                 // 49152 B
    __shared__ unsigned char bp_lds[(SEQ - 1) * NS];  // 12282 B

    const int tid = threadIdx.x;

    // ---- Phase A: logits + softmax per timestep ----
    for (int t = tid; t < SEQ; t += G3) {
        const float4* f4 = (const float4*)(fwd + (size_t)t * HID);
        const float4* b4 = (const float4*)(bwd + (size_t)t * HID);
        float lg[NS];
#pragma unroll
        for (int s = 0; s < NS; ++s) lg[s] = b_out[s];
#pragma unroll 4
        for (int k4 = 0; k4 < 32; ++k4) {
            const float4 fv = f4[k4];
            const float4 bv = b4[k4];
#pragma unroll
            for (int s = 0; s < NS; ++s) {
                const float4 wf = ((const float4*)(W_out + s * 256))[k4];
                const float4 wb = ((const float4*)(W_out + s * 256 + HID))[k4];
                lg[s] += wf.x * fv.x + wf.y * fv.y + wf.z * fv.z + wf.w * fv.w
                       + wb.x * bv.x + wb.y * bv.y + wb.z * bv.z + wb.w * bv.w;
            }
        }
        // stable softmax over 6
        float m = lg[0];
#pragma unroll
        for (int s = 1; s < NS; ++s) m = fmaxf(m, lg[s]);
        float sum = 0.f;
#pragma unroll
        for (int s = 0; s < NS; ++s) { lg[s] = __expf(lg[s] - m); sum += lg[s]; }
        const float inv = 1.f / sum;
#pragma unroll
        for (int s = 0; s < NS; ++s) p_lds[t * NS + s] = lg[s] * inv;
    }
    __syncthreads();

    // ---- Phase B: Viterbi forward (wave 0, lanes 0..5 active) ----
    float tr = -3.0e38f;
    if (tid < 64) {
        const int j = tid;
        const bool act = (j < NS);
        float tc[NS];
#pragma unroll
        for (int i = 0; i < NS; ++i) tc[i] = act ? trans[i * NS + j] : 0.f;
        if (act) tr = p_lds[j];

        for (int t = 1; t < SEQ; ++t) {
            const float pv = act ? p_lds[t * NS + j] : 0.f;
            // first-max semantics (strict >, ascending i) == jnp.argmax
            float best = __shfl(tr, 0) + tc[0]; int bi = 0;
            float v;
            v = __shfl(tr, 1) + tc[1]; if (v > best) { best = v; bi = 1; }
            v = __shfl(tr, 2) + tc[2]; if (v > best) { best = v; bi = 2; }
            v = __shfl(tr, 3) + tc[3]; if (v > best) { best = v; bi = 3; }
            v = __shfl(tr, 4) + tc[4]; if (v > best) { best = v; bi = 4; }
            v = __shfl(tr, 5) + tc[5]; if (v > best) { best = v; bi = 5; }
            if (act) {
                bp_lds[(t - 1) * NS + j] = (unsigned char)bi;
                tr = pv + best;
            }
        }
    }
    __syncthreads();   // order bp_lds writes before lane-0 backtrack reads

    // ---- Phase C: final argmax + backtrack (lane 0) ----
    if (tid < 64) {
        float best = __shfl(tr, 0); int bi = 0;
        float v;
        v = __shfl(tr, 1); if (v > best) { best = v; bi = 1; }
        v = __shfl(tr, 2); if (v > best) { best = v; bi = 2; }
        v = __shfl(tr, 3); if (v > best) { best = v; bi = 3; }
        v = __shfl(tr, 4); if (v > best) { best = v; bi = 4; }
        v = __shfl(tr, 5); if (v > best) { best = v; bi = 5; }
        if (tid == 0) {
            out[0] = best;                 // score
            int cur = bi;
            out[1 + (SEQ - 1)] = (float)cur;
            for (int t = SEQ - 1; t >= 1; --t) {
                cur = bp_lds[(t - 1) * NS + cur];
                out[t] = (float)cur;       // out[1 + (t-1)]
            }
        }
    }
}

// ---------------------------------------------------------------------------
extern "C" void kernel_launch(void* const* d_in, const int* in_sizes, int n_in,
                              void* d_out, int out_size, void* d_ws, size_t ws_size,
                              hipStream_t stream)
{
    (void)in_sizes; (void)n_in; (void)out_size; (void)ws_size;

    const int*   sent  = (const int*)  d_in[0];
    const float* emb   = (const float*)d_in[1];
    const float* h0    = (const float*)d_in[2];
    const float* Wf_ih = (const float*)d_in[3];
    const float* Wf_hh = (const float*)d_in[4];
    const float* bf_ih = (const float*)d_in[5];
    const float* bf_hh = (const float*)d_in[6];
    const float* Wb_ih = (const float*)d_in[7];
    const float* Wb_hh = (const float*)d_in[8];
    const float* bb_ih = (const float*)d_in[9];
    const float* bb_hh = (const float*)d_in[10];
    const float* W_out = (const float*)d_in[11];
    const float* b_out = (const float*)d_in[12];
    const float* trans = (const float*)d_in[13];
    float* out = (float*)d_out;

    // workspace layout (floats): gi_f[SEQ*G3] | gi_b[SEQ*G3] | fwd[SEQ*HID] | bwd[SEQ*HID]
    float* ws   = (float*)d_ws;
    float* gi_f = ws;
    float* gi_b = ws + (size_t)SEQ * G3;
    float* fwdb = ws + (size_t)2 * SEQ * G3;
    float* bwdb = fwdb + (size_t)SEQ * HID;

    k_input_proj<<<SEQ, G3, 0, stream>>>(sent, emb, Wf_ih, bf_ih, Wb_ih, bb_ih, gi_f, gi_b);
    k_recur<<<2, 768, 0, stream>>>(gi_f, gi_b, Wf_hh, bf_hh, Wb_hh, bb_hh, h0, fwdb, bwdb);
    k_out_viterbi<<<1, G3, 0, stream>>>(fwdb, bwdb, W_out, b_out, trans, out);
}

// Round 2
// 2065.592 us; speedup vs baseline: 1.5224x; 1.5224x over previous
//
#include <hip/hip_runtime.h>
#include <math.h>

// Problem constants (from reference setup_inputs)
constexpr int SEQ  = 2048;  // T
constexpr int BATCH = 64;   // B
constexpr int EMB  = 100;   // E
constexpr int HID  = 128;   // H
constexpr int G3   = 384;   // 3*H
constexpr int NS   = 6;     // S (CRF states)
constexpr int BSEL = 63;    // only batch row 63 affects the output

// DPP quad_perm cross-lane adds (VALU pipe — keeps reduction off the LDS pipe)
__device__ __forceinline__ float dpp_add_xor1(float x) {
    int v = __builtin_amdgcn_update_dpp(0, __float_as_int(x), 0xB1, 0xF, 0xF, true); // quad_perm(1,0,3,2)
    return x + __int_as_float(v);
}
__device__ __forceinline__ float dpp_add_xor2(float x) {
    int v = __builtin_amdgcn_update_dpp(0, __float_as_int(x), 0x4E, 0xF, 0xF, true); // quad_perm(2,3,0,1)
    return x + __int_as_float(v);
}

// ---------------------------------------------------------------------------
// Kernel 1: embedding lookup + input projection for batch row 63 only.
// ---------------------------------------------------------------------------
__global__ __launch_bounds__(G3) void k_input_proj(
    const int* __restrict__ sent, const float* __restrict__ emb,
    const float* __restrict__ Wf_ih, const float* __restrict__ bf_ih,
    const float* __restrict__ Wb_ih, const float* __restrict__ bb_ih,
    float* __restrict__ gi_f, float* __restrict__ gi_b)
{
    const int t = blockIdx.x;
    const int j = threadIdx.x;            // 0..383
    __shared__ float x_s[EMB];

    const int tok = sent[BSEL * SEQ + t];
    if (j < EMB) x_s[j] = emb[(size_t)tok * EMB + j];
    __syncthreads();

    const float* wf = Wf_ih + (size_t)j * EMB;
    const float* wb = Wb_ih + (size_t)j * EMB;
    float af = 0.f, ab = 0.f;
#pragma unroll 4
    for (int k = 0; k < EMB; ++k) {
        const float xv = x_s[k];
        af += wf[k] * xv;
        ab += wb[k] * xv;
    }
    gi_f[t * G3 + j] = af + bf_ih[j];
    gi_b[t * G3 + j] = ab + bb_ih[j];
}

// ---------------------------------------------------------------------------
// Kernel 2: sequential GRU recurrence, one block per direction.
// 512 threads: thread = (unit u = tid>>2, k-chunk kc = tid&3).
// Each thread holds rows {u, 128+u, 256+u} x cols [32*kc,32*kc+32) in VGPRs
// (96 regs), reads 32 h-floats/step from LDS (bank-staggered by kc), reduces
// the 4 kc-partials with DPP quad adds, and the kc==0 lane computes the gates
// for unit u locally. Double-buffered h -> ONE barrier per step.
// ---------------------------------------------------------------------------
__global__ __launch_bounds__(512, 2) void k_recur(
    const float* __restrict__ gi_f, const float* __restrict__ gi_b,
    const float* __restrict__ Wf_hh, const float* __restrict__ bf_hh,
    const float* __restrict__ Wb_hh, const float* __restrict__ bb_hh,
    const float* __restrict__ h0,
    float* __restrict__ fwd, float* __restrict__ bwd)
{
    const int dir = blockIdx.x;           // 0 = forward, 1 = backward
    const float* gi  = dir ? gi_b  : gi_f;
    const float* Whh = dir ? Wb_hh : Wf_hh;
    const float* bhh = dir ? bb_hh : bf_hh;
    float* outs      = dir ? bwd   : fwd;

    const int tid = threadIdx.x;          // 0..511
    const int u   = tid >> 2;             // hidden unit 0..127
    const int kc  = tid & 3;              // 32-wide k chunk
    const int kc2 = 2 * kc;               // bank stagger

    // Weight fragments -> VGPRs, pre-rotated so step-m reads hit disjoint banks.
    float4 wr[8], wz[8], wn[8];
    {
        const float4* Rr = (const float4*)(Whh + (size_t)u * HID);
        const float4* Rz = (const float4*)(Whh + (size_t)(HID + u) * HID);
        const float4* Rn = (const float4*)(Whh + (size_t)(2 * HID + u) * HID);
#pragma unroll
        for (int m = 0; m < 8; ++m) {
            const int i2 = (m + kc2) & 7;
            wr[m] = Rr[8 * kc + i2];
            wz[m] = Rz[8 * kc + i2];
            wn[m] = Rn[8 * kc + i2];
        }
    }

    float br = 0.f, bz = 0.f, bn = 0.f, h_u = 0.f;
    float gr_c = 0.f, gz_c = 0.f, gn_c = 0.f;   // current-step gi (kc==0)
    if (kc == 0) {
        br = bhh[u]; bz = bhh[HID + u]; bn = bhh[2 * HID + u];
        h_u = h0[(size_t)dir * BATCH * HID + BSEL * HID + u];
        const int t0 = dir ? (SEQ - 1) : 0;
        gr_c = gi[t0 * G3 + u];
        gz_c = gi[t0 * G3 + HID + u];
        gn_c = gi[t0 * G3 + 2 * HID + u];
    }

    __shared__ __align__(16) float h_lds[2][HID];
    if (tid < HID) h_lds[0][tid] = h0[(size_t)dir * BATCH * HID + BSEL * HID + tid];
    __syncthreads();

    for (int step = 0; step < SEQ; ++step) {
        const int t   = dir ? (SEQ - 1 - step) : step;
        const int cur = step & 1;
        const int nxt = cur ^ 1;

        // prefetch next step's gi early (hidden under the dot product)
        float gr_n = 0.f, gz_n = 0.f, gn_n = 0.f;
        if (kc == 0 && step + 1 < SEQ) {
            const int tn = dir ? (SEQ - 2 - step) : (step + 1);
            gr_n = gi[tn * G3 + u];
            gz_n = gi[tn * G3 + HID + u];
            gn_n = gi[tn * G3 + 2 * HID + u];
        }

        // partial dots over this thread's 32 columns (bank-staggered reads)
        const float4* h4 = (const float4*)(h_lds[cur]);
        float ar = 0.f, az = 0.f, an = 0.f;
#pragma unroll
        for (int m = 0; m < 8; ++m) {
            const int i2 = (m + kc2) & 7;
            const float4 hv = h4[8 * kc + i2];
            ar += wr[m].x * hv.x + wr[m].y * hv.y + wr[m].z * hv.z + wr[m].w * hv.w;
            az += wz[m].x * hv.x + wz[m].y * hv.y + wz[m].z * hv.z + wz[m].w * hv.w;
            an += wn[m].x * hv.x + wn[m].y * hv.y + wn[m].z * hv.z + wn[m].w * hv.w;
        }
        // reduce across the 4 kc lanes (same quad) on the VALU pipe
        ar = dpp_add_xor2(dpp_add_xor1(ar));
        az = dpp_add_xor2(dpp_add_xor1(az));
        an = dpp_add_xor2(dpp_add_xor1(an));

        if (kc == 0) {
            const float r = 1.f / (1.f + __expf(-(gr_c + ar + br)));
            const float z = 1.f / (1.f + __expf(-(gz_c + az + bz)));
            const float n = tanhf(gn_c + r * (an + bn));
            h_u = (1.f - z) * n + z * h_u;
            h_lds[nxt][u] = h_u;
            outs[(size_t)t * HID + u] = h_u;
            gr_c = gr_n; gz_c = gz_n; gn_c = gn_n;
        }
        __syncthreads();   // h_lds[nxt] visible to everyone for next step
    }
}

// ---------------------------------------------------------------------------
// Kernel 3: logits + softmax -> LDS, exact serial Viterbi forward (6 lanes),
// then CHUNKED backtrack: 32 chunks x 6 states walk in parallel, serial
// splice over 32 boundaries, parallel emit. Integer-exact (same path).
// ---------------------------------------------------------------------------
__global__ __launch_bounds__(G3) void k_out_viterbi(
    const float* __restrict__ fwd, const float* __restrict__ bwd,
    const float* __restrict__ W_out, const float* __restrict__ b_out,
    const float* __restrict__ trans, float* __restrict__ out)
{
    __shared__ float p_lds[SEQ * NS];                 // 49152 B
    __shared__ unsigned char bp_lds[(SEQ - 1) * NS];  // 12282 B
    __shared__ unsigned char cmap[32 * NS];           // chunk state maps
    __shared__ int bstate[32];                        // state at time 64*c
    __shared__ int s_last;

    const int tid = threadIdx.x;

    // ---- Phase A: logits + softmax per timestep ----
    for (int t = tid; t < SEQ; t += G3) {
        const float4* f4 = (const float4*)(fwd + (size_t)t * HID);
        const float4* b4 = (const float4*)(bwd + (size_t)t * HID);
        float lg[NS];
#pragma unroll
        for (int s = 0; s < NS; ++s) lg[s] = b_out[s];
#pragma unroll 4
        for (int k4 = 0; k4 < 32; ++k4) {
            const float4 fv = f4[k4];
            const float4 bv = b4[k4];
#pragma unroll
            for (int s = 0; s < NS; ++s) {
                const float4 wf = ((const float4*)(W_out + s * 256))[k4];
                const float4 wb = ((const float4*)(W_out + s * 256 + HID))[k4];
                lg[s] += wf.x * fv.x + wf.y * fv.y + wf.z * fv.z + wf.w * fv.w
                       + wb.x * bv.x + wb.y * bv.y + wb.z * bv.z + wb.w * bv.w;
            }
        }
        float m = lg[0];
#pragma unroll
        for (int s = 1; s < NS; ++s) m = fmaxf(m, lg[s]);
        float sum = 0.f;
#pragma unroll
        for (int s = 0; s < NS; ++s) { lg[s] = __expf(lg[s] - m); sum += lg[s]; }
        const float inv = 1.f / sum;
#pragma unroll
        for (int s = 0; s < NS; ++s) p_lds[t * NS + s] = lg[s] * inv;
    }
    __syncthreads();

    // ---- Phase B: exact serial Viterbi forward (wave 0, lanes 0..5) ----
    float tr = -3.0e38f;
    if (tid < 64) {
        const int j = tid;
        const bool act = (j < NS);
        float tc[NS];
#pragma unroll
        for (int i = 0; i < NS; ++i) tc[i] = act ? trans[i * NS + j] : 0.f;
        if (act) tr = p_lds[j];

        for (int t = 1; t < SEQ; ++t) {
            const float pv = act ? p_lds[t * NS + j] : 0.f;
            float best = __shfl(tr, 0) + tc[0]; int bi = 0;
            float v;
            v = __shfl(tr, 1) + tc[1]; if (v > best) { best = v; bi = 1; }
            v = __shfl(tr, 2) + tc[2]; if (v > best) { best = v; bi = 2; }
            v = __shfl(tr, 3) + tc[3]; if (v > best) { best = v; bi = 3; }
            v = __shfl(tr, 4) + tc[4]; if (v > best) { best = v; bi = 4; }
            v = __shfl(tr, 5) + tc[5]; if (v > best) { best = v; bi = 5; }
            if (act) {
                bp_lds[(t - 1) * NS + j] = (unsigned char)bi;
                tr = pv + best;
            }
        }
        // final argmax over 6 trellis values
        float best = __shfl(tr, 0); int bi = 0;
        float v;
        v = __shfl(tr, 1); if (v > best) { best = v; bi = 1; }
        v = __shfl(tr, 2); if (v > best) { best = v; bi = 2; }
        v = __shfl(tr, 3); if (v > best) { best = v; bi = 3; }
        v = __shfl(tr, 4); if (v > best) { best = v; bi = 4; }
        v = __shfl(tr, 5); if (v > best) { best = v; bi = 5; }
        if (tid == 0) { out[0] = best; s_last = bi; }
    }
    __syncthreads();

    // ---- Phase C1: per-chunk backpointer composition (192 walkers) ----
    // chunk c spans times (64c, hi_c], hi_c = min(64(c+1), 2047)
    if (tid < 32 * NS) {
        const int c = tid / NS, s0 = tid % NS;
        const int hi = (c == 31) ? (SEQ - 1) : 64 * (c + 1);
        const int lo = 64 * c;
        int s = s0;
        for (int tau = hi; tau > lo; --tau) s = bp_lds[(tau - 1) * NS + s];
        cmap[c * NS + s0] = (unsigned char)s;
    }
    __syncthreads();

    // ---- Phase C2: serial splice over 32 chunk boundaries ----
    if (tid == 0) {
        int s = s_last;                    // state at time SEQ-1
        for (int c = 31; c >= 0; --c) {
            s = cmap[c * NS + s];          // state at time 64*c
            bstate[c] = s;
        }
    }
    __syncthreads();

    // ---- Phase C3: parallel emit (32 chunks re-walk) ----
    if (tid < 32) {
        const int c = tid;
        const int hi = (c == 31) ? (SEQ - 1) : 64 * (c + 1);
        const int lo = 64 * c;
        int s = (c == 31) ? s_last : bstate[c + 1];
        for (int tau = hi; tau > lo; --tau) {
            out[1 + tau] = (float)s;
            s = bp_lds[(tau - 1) * NS + s];
        }
        if (c == 0) out[1] = (float)s;     // time 0... wait: writes below
    }
    // note: loop wrote times (lo, hi]; time 0 handled by c==0 after its loop:
    // after the loop above, s == state at time lo. For c==0 that's time 0.
    if (tid == 0) { /* placeholder to keep structure clear */ }
    __syncthreads();
    if (tid < 32 && tid == 0) {
        // recompute state at time 0 exactly as c==0 walker ended: emitted above
    }
}

// ---------------------------------------------------------------------------
extern "C" void kernel_launch(void* const* d_in, const int* in_sizes, int n_in,
                              void* d_out, int out_size, void* d_ws, size_t ws_size,
                              hipStream_t stream)
{
    (void)in_sizes; (void)n_in; (void)out_size; (void)ws_size;

    const int*   sent  = (const int*)  d_in[0];
    const float* emb   = (const float*)d_in[1];
    const float* h0    = (const float*)d_in[2];
    const float* Wf_ih = (const float*)d_in[3];
    const float* Wf_hh = (const float*)d_in[4];
    const float* bf_ih = (const float*)d_in[5];
    const float* bf_hh = (const float*)d_in[6];
    const float* Wb_ih = (const float*)d_in[7];
    const float* Wb_hh = (const float*)d_in[8];
    const float* bb_ih = (const float*)d_in[9];
    const float* bb_hh = (const float*)d_in[10];
    const float* W_out = (const float*)d_in[11];
    const float* b_out = (const float*)d_in[12];
    const float* trans = (const float*)d_in[13];
    float* out = (float*)d_out;

    // workspace layout (floats): gi_f[SEQ*G3] | gi_b[SEQ*G3] | fwd[SEQ*HID] | bwd[SEQ*HID]
    float* ws   = (float*)d_ws;
    float* gi_f = ws;
    float* gi_b = ws + (size_t)SEQ * G3;
    float* fwdb = ws + (size_t)2 * SEQ * G3;
    float* bwdb = fwdb + (size_t)SEQ * HID;

    k_input_proj<<<SEQ, G3, 0, stream>>>(sent, emb, Wf_ih, bf_ih, Wb_ih, bb_ih, gi_f, gi_b);
    k_recur<<<2, 512, 0, stream>>>(gi_f, gi_b, Wf_hh, bf_hh, Wb_hh, bb_hh, h0, fwdb, bwdb);
    k_out_viterbi<<<1, G3, 0, stream>>>(fwdb, bwdb, W_out, b_out, trans, out);
}

// Round 4
// 1933.177 us; speedup vs baseline: 1.6267x; 1.0685x over previous
//
#include <hip/hip_runtime.h>
#include <math.h>

// Problem constants (from reference setup_inputs)
constexpr int SEQ   = 2048;  // T
constexpr int BATCH = 64;    // B
constexpr int EMB   = 100;   // E
constexpr int HID   = 128;   // H
constexpr int G3    = 384;   // 3*H
constexpr int NS    = 6;     // S (CRF states)
constexpr int BSEL  = 63;    // only batch row 63 affects the output

// Opaque register pin on a SCALAR float (single VGPR — supported by LLVM).
#define KEEPF(v) asm volatile("" : "+v"(v))

// DPP cross-lane adds (VALU pipe, no LDS)
// xor1 = quad_perm(1,0,3,2)=0xB1, xor2 = quad_perm(2,3,0,1)=0x4E,
// xor8 = row_ror:8 = 0x128 (ror by 8 within a 16-lane row == xor 8)
template <int CTRL>
__device__ __forceinline__ float dpp_add(float x) {
    int v = __builtin_amdgcn_update_dpp(0, __float_as_int(x), CTRL, 0xF, 0xF, true);
    return x + __int_as_float(v);
}

__device__ __forceinline__ float bperm_f(int srclane, float x) {
    return __int_as_float(__builtin_amdgcn_ds_bpermute(srclane * 4, __float_as_int(x)));
}

// ---------------------------------------------------------------------------
// Kernel 1: embedding lookup + input projection for batch row 63 only.
// 4 timesteps per block; weight rows register-cached across the 4 t's.
// ---------------------------------------------------------------------------
__global__ __launch_bounds__(G3) void k_input_proj(
    const int* __restrict__ sent, const float* __restrict__ emb,
    const float* __restrict__ Wf_ih, const float* __restrict__ bf_ih,
    const float* __restrict__ Wb_ih, const float* __restrict__ bb_ih,
    float* __restrict__ gi_f, float* __restrict__ gi_b)
{
    const int tb = blockIdx.x * 4;
    const int j  = threadIdx.x;           // 0..383
    __shared__ __align__(16) float x_s[4][EMB];

    int toks[4];
#pragma unroll
    for (int tt = 0; tt < 4; ++tt) toks[tt] = sent[BSEL * SEQ + tb + tt];
    if (j < EMB) {
#pragma unroll
        for (int tt = 0; tt < 4; ++tt)
            x_s[tt][j] = emb[(size_t)toks[tt] * EMB + j];
    }
    __syncthreads();

    // weight rows -> registers (reused for 4 timesteps)
    float4 wf4[25], wb4[25];
    const float4* wfp = (const float4*)(Wf_ih + (size_t)j * EMB);
    const float4* wbp = (const float4*)(Wb_ih + (size_t)j * EMB);
#pragma unroll
    for (int m = 0; m < 25; ++m) { wf4[m] = wfp[m]; wb4[m] = wbp[m]; }
    const float bf = bf_ih[j], bb = bb_ih[j];

#pragma unroll
    for (int tt = 0; tt < 4; ++tt) {
        const float4* xs = (const float4*)(x_s[tt]);
        float af = 0.f, ab = 0.f;
#pragma unroll
        for (int m = 0; m < 25; ++m) {
            const float4 xv = xs[m];
            af = fmaf(wf4[m].x, xv.x, af); af = fmaf(wf4[m].y, xv.y, af);
            af = fmaf(wf4[m].z, xv.z, af); af = fmaf(wf4[m].w, xv.w, af);
            ab = fmaf(wb4[m].x, xv.x, ab); ab = fmaf(wb4[m].y, xv.y, ab);
            ab = fmaf(wb4[m].z, xv.z, ab); ab = fmaf(wb4[m].w, xv.w, ab);
        }
        gi_f[(tb + tt) * G3 + j] = af + bf;
        gi_b[(tb + tt) * G3 + j] = ab + bb;
    }
}

// ---------------------------------------------------------------------------
// Kernel 2: sequential GRU recurrence, one block (512 thr) per direction.
// Thread = (u2 = unit-pair 0..63, kc = 16-col chunk 0..7).
//   kc on lane bits {0,1,3}; unit-group on bits {2,4,5} (+ wave id).
// 96 scalar weights pinned in VGPRs; 4 bank-rotated ds_read_b128 per step;
// 3-stage DPP allreduce; one barrier per step (double-buffered h).
// ---------------------------------------------------------------------------
__global__ __launch_bounds__(512, 2) void k_recur(
    const float* __restrict__ gi_f, const float* __restrict__ gi_b,
    const float* __restrict__ Wf_hh, const float* __restrict__ bf_hh,
    const float* __restrict__ Wb_hh, const float* __restrict__ bb_hh,
    const float* __restrict__ h0,
    float* __restrict__ fwd, float* __restrict__ bwd)
{
    const int dir = blockIdx.x;           // 0 = forward, 1 = backward
    const float* gi  = dir ? gi_b  : gi_f;
    const float* Whh = dir ? Wb_hh : Wf_hh;
    const float* bhh = dir ? bb_hh : bf_hh;
    float* outs      = dir ? bwd   : fwd;

    const int tid  = threadIdx.x;
    const int lane = tid & 63;
    const int wv   = tid >> 6;                              // 0..7
    const int kc   = (lane & 3) | ((lane >> 1) & 4);        // bits 0,1,3 -> 0..7
    const int g    = ((lane >> 2) & 1) | ((lane >> 3) & 6); // bits 2,4,5 -> 0..7
    const int u2   = wv * 8 + g;                            // 0..63
    const int ua   = 2 * u2;                                // even unit

    // --- weight fragments -> pinned scalar VGPRs.
    // Slot m4 of this thread holds float4 column (kc*4 + ((m4+kc)&3)) — the
    // same rotated index the h-reads use, so dot pairs match and the 8 kc
    // lanes hit disjoint banks (only kc<->kc+4 alias = free 2-way).
    float W[6][16];
    {
        const float4* Wp = (const float4*)Whh;
#pragma unroll
        for (int rr = 0; rr < 6; ++rr) {
            const int row = (rr >> 1) * HID + ua + (rr & 1);
#pragma unroll
            for (int m4 = 0; m4 < 4; ++m4) {
                const int col4 = kc * 4 + ((m4 + kc) & 3);
                const float4 wv4 = Wp[row * 32 + col4];
                W[rr][m4 * 4 + 0] = wv4.x; W[rr][m4 * 4 + 1] = wv4.y;
                W[rr][m4 * 4 + 2] = wv4.z; W[rr][m4 * 4 + 3] = wv4.w;
            }
        }
#pragma unroll
        for (int rr = 0; rr < 6; ++rr)
#pragma unroll
            for (int m = 0; m < 16; ++m) KEEPF(W[rr][m]);
    }

    float b_ra = bhh[ua],           b_rb = bhh[ua + 1];
    float b_za = bhh[HID + ua],     b_zb = bhh[HID + ua + 1];
    float b_na = bhh[2 * HID + ua], b_nb = bhh[2 * HID + ua + 1];
    KEEPF(b_ra); KEEPF(b_rb); KEEPF(b_za); KEEPF(b_zb); KEEPF(b_na); KEEPF(b_nb);

    const int ginc = dir ? -G3 : G3;
    const int oinc = dir ? -HID : HID;
    const int t0   = dir ? (SEQ - 1) : 0;
    const float* gp = gi + (size_t)t0 * G3 + ua;
    float* op       = outs + (size_t)t0 * HID + ua;

    const float2 h2 = *(const float2*)(h0 + (size_t)dir * BATCH * HID + BSEL * HID + ua);
    float h_a = h2.x, h_b = h2.y;

    float gc0, gc1, gc2, gc3, gc4, gc5;   // current-step gi (+folded bhh for r,z)
    {
        const float2 r2 = *(const float2*)gp;
        const float2 z2 = *(const float2*)(gp + 128);
        const float2 n2 = *(const float2*)(gp + 256);
        gc0 = r2.x + b_ra; gc1 = r2.y + b_rb;
        gc2 = z2.x + b_za; gc3 = z2.y + b_zb;
        gc4 = n2.x;        gc5 = n2.y;
    }

    __shared__ __align__(16) float h_lds[2][HID];
    if (tid < HID) h_lds[0][tid] = h0[(size_t)dir * BATCH * HID + BSEL * HID + tid];
    __syncthreads();

    auto body = [&](int cur) {
        // prefetch next step's gi (address always lands inside the workspace:
        // dir=0 overruns into gi_b's first row, dir=1 into gi_f's last row —
        // both valid memory; values discarded on the final step)
        const float* gpn = gp + ginc;
        const float2 r2 = *(const float2*)gpn;
        const float2 z2 = *(const float2*)(gpn + 128);
        const float2 n2 = *(const float2*)(gpn + 256);

        // partial dots over 16 cols for 6 rows (bank-rotated reads)
        const float4* h4 = (const float4*)(h_lds[cur]);
        float a0 = 0.f, a1 = 0.f, a2 = 0.f, a3 = 0.f, a4 = 0.f, a5 = 0.f;
#pragma unroll
        for (int m4 = 0; m4 < 4; ++m4) {
            const float4 hv = h4[kc * 4 + ((m4 + kc) & 3)];
#define DOT4(acc, rr) \
            acc = fmaf(W[rr][m4*4+0], hv.x, acc); acc = fmaf(W[rr][m4*4+1], hv.y, acc); \
            acc = fmaf(W[rr][m4*4+2], hv.z, acc); acc = fmaf(W[rr][m4*4+3], hv.w, acc)
            DOT4(a0, 0); DOT4(a1, 1); DOT4(a2, 2);
            DOT4(a3, 3); DOT4(a4, 4); DOT4(a5, 5);
#undef DOT4
        }
        // allreduce over the 8 kc lanes (bits 0,1,3) — pure VALU DPP
        a0 = dpp_add<0x128>(dpp_add<0x4E>(dpp_add<0xB1>(a0)));
        a1 = dpp_add<0x128>(dpp_add<0x4E>(dpp_add<0xB1>(a1)));
        a2 = dpp_add<0x128>(dpp_add<0x4E>(dpp_add<0xB1>(a2)));
        a3 = dpp_add<0x128>(dpp_add<0x4E>(dpp_add<0xB1>(a3)));
        a4 = dpp_add<0x128>(dpp_add<0x4E>(dpp_add<0xB1>(a4)));
        a5 = dpp_add<0x128>(dpp_add<0x4E>(dpp_add<0xB1>(a5)));

        // gates (all lanes redundantly — identical fp trajectories)
        const float ra = __builtin_amdgcn_rcpf(1.f + __expf(-(gc0 + a0)));
        const float rb = __builtin_amdgcn_rcpf(1.f + __expf(-(gc1 + a1)));
        const float za = __builtin_amdgcn_rcpf(1.f + __expf(-(gc2 + a2)));
        const float zb = __builtin_amdgcn_rcpf(1.f + __expf(-(gc3 + a3)));
        float ta = gc4 + ra * (a4 + b_na); ta = fminf(fmaxf(ta, -15.f), 15.f);
        float tb = gc5 + rb * (a5 + b_nb); tb = fminf(fmaxf(tb, -15.f), 15.f);
        const float ea = __expf(-2.f * ta), eb = __expf(-2.f * tb);
        const float na = (1.f - ea) * __builtin_amdgcn_rcpf(1.f + ea);
        const float nb = (1.f - eb) * __builtin_amdgcn_rcpf(1.f + eb);
        h_a = (1.f - za) * na + za * h_a;
        h_b = (1.f - zb) * nb + zb * h_b;

        if (kc == 0) {
            ((float2*)(h_lds[cur ^ 1]))[u2] = float2{h_a, h_b};
            *(float2*)op = float2{h_a, h_b};
        }
        gc0 = r2.x + b_ra; gc1 = r2.y + b_rb;
        gc2 = z2.x + b_za; gc3 = z2.y + b_zb;
        gc4 = n2.x;        gc5 = n2.y;
        gp = gpn; op += oinc;
        __syncthreads();
    };

    for (int step = 0; step < SEQ; step += 2) { body(0); body(1); }
}

// ---------------------------------------------------------------------------
// Kernel 3: logits + softmax -> LDS; serial Viterbi forward with batched
// ds_bpermute allgather + fmax tree / equality first-argmax (exact);
// chunked backtrack. One block, 384 threads.
// ---------------------------------------------------------------------------
__global__ __launch_bounds__(G3) void k_out_viterbi(
    const float* __restrict__ fwd, const float* __restrict__ bwd,
    const float* __restrict__ W_out, const float* __restrict__ b_out,
    const float* __restrict__ trans, float* __restrict__ out)
{
    __shared__ float p_lds[(SEQ + 1) * NS];           // +1 pad row for prefetch
    __shared__ unsigned char bp_lds[(SEQ - 1) * NS];
    __shared__ unsigned char cmap[32 * NS];
    __shared__ int bstate[32];
    __shared__ int s_last;

    const int tid = threadIdx.x;

    // ---- Phase A: logits + softmax per timestep ----
    for (int t = tid; t < SEQ; t += G3) {
        const float4* f4 = (const float4*)(fwd + (size_t)t * HID);
        const float4* b4 = (const float4*)(bwd + (size_t)t * HID);
        float lg[NS];
#pragma unroll
        for (int s = 0; s < NS; ++s) lg[s] = b_out[s];
#pragma unroll 4
        for (int k4 = 0; k4 < 32; ++k4) {
            const float4 fv = f4[k4];
            const float4 bv = b4[k4];
#pragma unroll
            for (int s = 0; s < NS; ++s) {
                const float4 wf = ((const float4*)(W_out + s * 256))[k4];
                const float4 wb = ((const float4*)(W_out + s * 256 + HID))[k4];
                lg[s] += wf.x * fv.x + wf.y * fv.y + wf.z * fv.z + wf.w * fv.w
                       + wb.x * bv.x + wb.y * bv.y + wb.z * bv.z + wb.w * bv.w;
            }
        }
        float m = lg[0];
#pragma unroll
        for (int s = 1; s < NS; ++s) m = fmaxf(m, lg[s]);
        float sum = 0.f;
#pragma unroll
        for (int s = 0; s < NS; ++s) { lg[s] = __expf(lg[s] - m); sum += lg[s]; }
        const float inv = 1.f / sum;
#pragma unroll
        for (int s = 0; s < NS; ++s) p_lds[t * NS + s] = lg[s] * inv;
    }
    __syncthreads();

    // ---- Phase B: exact serial Viterbi forward (wave 0, lanes 0..5) ----
    if (tid < 64) {
        const int j = tid;
        const bool act = (j < NS);
        const int jc = act ? j : 0;            // clamped index for LDS prefetch
        float tc0 = act ? trans[0 * NS + j] : 0.f;
        float tc1 = act ? trans[1 * NS + j] : 0.f;
        float tc2 = act ? trans[2 * NS + j] : 0.f;
        float tc3 = act ? trans[3 * NS + j] : 0.f;
        float tc4 = act ? trans[4 * NS + j] : 0.f;
        float tc5 = act ? trans[5 * NS + j] : 0.f;
        float tr = act ? p_lds[j] : -3.0e38f;
        float pv = p_lds[NS + jc];             // prob for t=1

        for (int t = 1; t < SEQ; ++t) {
            // batched allgather of tr (6 bpermutes, single wait)
            const float v0 = bperm_f(0, tr) + tc0;
            const float v1 = bperm_f(1, tr) + tc1;
            const float v2 = bperm_f(2, tr) + tc2;
            const float v3 = bperm_f(3, tr) + tc3;
            const float v4 = bperm_f(4, tr) + tc4;
            const float v5 = bperm_f(5, tr) + tc5;
            const float pnext = p_lds[(t + 1) * NS + jc];  // pad row at t=SEQ-1
            // exact max tree on the critical path
            const float best = fmaxf(fmaxf(fmaxf(v0, v1), v2),
                                     fmaxf(fmaxf(v3, v4), v5));
            const float trn = pv + best;
            // first-argmax via equality (off critical path) == jnp.argmax
            int bi = 5;
            bi = (v4 == best) ? 4 : bi;
            bi = (v3 == best) ? 3 : bi;
            bi = (v2 == best) ? 2 : bi;
            bi = (v1 == best) ? 1 : bi;
            bi = (v0 == best) ? 0 : bi;
            if (act) bp_lds[(t - 1) * NS + j] = (unsigned char)bi;
            tr = act ? trn : tr;
            pv = pnext;
        }
        // final argmax over the 6 trellis values
        const float f0 = bperm_f(0, tr);
        const float f1 = bperm_f(1, tr);
        const float f2 = bperm_f(2, tr);
        const float f3 = bperm_f(3, tr);
        const float f4 = bperm_f(4, tr);
        const float f5 = bperm_f(5, tr);
        const float best = fmaxf(fmaxf(fmaxf(f0, f1), f2),
                                 fmaxf(fmaxf(f3, f4), f5));
        int bi = 5;
        bi = (f4 == best) ? 4 : bi;
        bi = (f3 == best) ? 3 : bi;
        bi = (f2 == best) ? 2 : bi;
        bi = (f1 == best) ? 1 : bi;
        bi = (f0 == best) ? 0 : bi;
        if (tid == 0) { out[0] = best; s_last = bi; }
    }
    __syncthreads();

    // ---- Phase C1: per-chunk backpointer composition (192 walkers) ----
    if (tid < 32 * NS) {
        const int c = tid / NS, s0 = tid % NS;
        const int hi = (c == 31) ? (SEQ - 1) : 64 * (c + 1);
        const int lo = 64 * c;
        int s = s0;
        for (int tau = hi; tau > lo; --tau) s = bp_lds[(tau - 1) * NS + s];
        cmap[c * NS + s0] = (unsigned char)s;
    }
    __syncthreads();

    // ---- Phase C2: serial splice over 32 chunk boundaries ----
    if (tid == 0) {
        int s = s_last;
        for (int c = 31; c >= 0; --c) {
            s = cmap[c * NS + s];
            bstate[c] = s;
        }
    }
    __syncthreads();

    // ---- Phase C3: parallel emit (32 chunks re-walk) ----
    if (tid < 32) {
        const int c = tid;
        const int hi = (c == 31) ? (SEQ - 1) : 64 * (c + 1);
        const int lo = 64 * c;
        int s = (c == 31) ? s_last : bstate[c + 1];
        for (int tau = hi; tau > lo; --tau) {
            out[1 + tau] = (float)s;
            s = bp_lds[(tau - 1) * NS + s];
        }
        if (c == 0) out[1] = (float)s;   // time 0
    }
}

// ---------------------------------------------------------------------------
extern "C" void kernel_launch(void* const* d_in, const int* in_sizes, int n_in,
                              void* d_out, int out_size, void* d_ws, size_t ws_size,
                              hipStream_t stream)
{
    (void)in_sizes; (void)n_in; (void)out_size; (void)ws_size;

    const int*   sent  = (const int*)  d_in[0];
    const float* emb   = (const float*)d_in[1];
    const float* h0    = (const float*)d_in[2];
    const float* Wf_ih = (const float*)d_in[3];
    const float* Wf_hh = (const float*)d_in[4];
    const float* bf_ih = (const float*)d_in[5];
    const float* bf_hh = (const float*)d_in[6];
    const float* Wb_ih = (const float*)d_in[7];
    const float* Wb_hh = (const float*)d_in[8];
    const float* bb_ih = (const float*)d_in[9];
    const float* bb_hh = (const float*)d_in[10];
    const float* W_out = (const float*)d_in[11];
    const float* b_out = (const float*)d_in[12];
    const float* trans = (const float*)d_in[13];
    float* out = (float*)d_out;

    // workspace layout (floats): gi_f[SEQ*G3] | gi_b[SEQ*G3] | fwd[SEQ*HID] | bwd[SEQ*HID]
    float* ws   = (float*)d_ws;
    float* gi_f = ws;
    float* gi_b = ws + (size_t)SEQ * G3;
    float* fwdb = ws + (size_t)2 * SEQ * G3;
    float* bwdb = fwdb + (size_t)SEQ * HID;

    k_input_proj<<<SEQ / 4, G3, 0, stream>>>(sent, emb, Wf_ih, bf_ih, Wb_ih, bb_ih, gi_f, gi_b);
    k_recur<<<2, 512, 0, stream>>>(gi_f, gi_b, Wf_hh, bf_hh, Wb_hh, bb_hh, h0, fwdb, bwdb);
    k_out_viterbi<<<1, G3, 0, stream>>>(fwdb, bwdb, W_out, b_out, trans, out);
}

// Round 5
// 1933.152 us; speedup vs baseline: 1.6267x; 1.0000x over previous
//
#include <hip/hip_runtime.h>
#include <math.h>

// Problem constants (from reference setup_inputs)
constexpr int SEQ   = 2048;  // T
constexpr int BATCH = 64;    // B
constexpr int EMB   = 100;   // E
constexpr int HID   = 128;   // H
constexpr int G3    = 384;   // 3*H
constexpr int NS    = 6;     // S (CRF states)
constexpr int BSEL  = 63;    // only batch row 63 affects the output

// Opaque register pin on a SCALAR float (single VGPR — supported by LLVM).
#define KEEPF(v) asm volatile("" : "+v"(v))

// DPP cross-lane adds (VALU pipe, no LDS)
// xor1 = quad_perm(1,0,3,2)=0xB1, xor2 = quad_perm(2,3,0,1)=0x4E,
// xor8 = row_ror:8 = 0x128 (ror by 8 within a 16-lane row == xor 8)
template <int CTRL>
__device__ __forceinline__ float dpp_add(float x) {
    int v = __builtin_amdgcn_update_dpp(0, __float_as_int(x), CTRL, 0xF, 0xF, true);
    return x + __int_as_float(v);
}

__device__ __forceinline__ float bperm_f(int srclane, float x) {
    return __int_as_float(__builtin_amdgcn_ds_bpermute(srclane * 4, __float_as_int(x)));
}

// ---------------------------------------------------------------------------
// Kernel 1: embedding lookup + input projection for batch row 63 only.
// 4 timesteps per block; weight rows register-cached across the 4 t's.
// ---------------------------------------------------------------------------
__global__ __launch_bounds__(G3) void k_input_proj(
    const int* __restrict__ sent, const float* __restrict__ emb,
    const float* __restrict__ Wf_ih, const float* __restrict__ bf_ih,
    const float* __restrict__ Wb_ih, const float* __restrict__ bb_ih,
    float* __restrict__ gi_f, float* __restrict__ gi_b)
{
    const int tb = blockIdx.x * 4;
    const int j  = threadIdx.x;           // 0..383
    __shared__ __align__(16) float x_s[4][EMB];

    int toks[4];
#pragma unroll
    for (int tt = 0; tt < 4; ++tt) toks[tt] = sent[BSEL * SEQ + tb + tt];
    if (j < EMB) {
#pragma unroll
        for (int tt = 0; tt < 4; ++tt)
            x_s[tt][j] = emb[(size_t)toks[tt] * EMB + j];
    }
    __syncthreads();

    // weight rows -> registers (reused for 4 timesteps)
    float4 wf4[25], wb4[25];
    const float4* wfp = (const float4*)(Wf_ih + (size_t)j * EMB);
    const float4* wbp = (const float4*)(Wb_ih + (size_t)j * EMB);
#pragma unroll
    for (int m = 0; m < 25; ++m) { wf4[m] = wfp[m]; wb4[m] = wbp[m]; }
    const float bf = bf_ih[j], bb = bb_ih[j];

#pragma unroll
    for (int tt = 0; tt < 4; ++tt) {
        const float4* xs = (const float4*)(x_s[tt]);
        float af = 0.f, ab = 0.f;
#pragma unroll
        for (int m = 0; m < 25; ++m) {
            const float4 xv = xs[m];
            af = fmaf(wf4[m].x, xv.x, af); af = fmaf(wf4[m].y, xv.y, af);
            af = fmaf(wf4[m].z, xv.z, af); af = fmaf(wf4[m].w, xv.w, af);
            ab = fmaf(wb4[m].x, xv.x, ab); ab = fmaf(wb4[m].y, xv.y, ab);
            ab = fmaf(wb4[m].z, xv.z, ab); ab = fmaf(wb4[m].w, xv.w, ab);
        }
        gi_f[(tb + tt) * G3 + j] = af + bf;
        gi_b[(tb + tt) * G3 + j] = ab + bb;
    }
}

// ---------------------------------------------------------------------------
// Kernel 2: sequential GRU recurrence, one block (512 thr) per direction.
// Thread = (u2 = unit-pair 0..63, kc = 16-col chunk 0..7).
//   kc on lane bits {0,1,3}; unit-group on bits {2,4,5} (+ wave id).
// 96 scalar weights pinned in VGPRs; 4 bank-rotated ds_read_b128 per step;
// 3-stage DPP allreduce; one barrier per step (double-buffered h).
//
// __launch_bounds__(512, 1): second arg is min BLOCKS per CU (CUDA
// semantics). (512,2) capped the unified file at 128 regs (64 arch +
// 64 acc) -> the 102 pinned floats were shuttled via AGPR/scratch every
// step (R4: VGPR_Count=64, no speedup). With 1 block/CU the cap is 256
// and the working set (~130) fits in arch VGPRs. Grid is 2 blocks total,
// so occupancy is irrelevant.
// ---------------------------------------------------------------------------
__global__ __launch_bounds__(512, 1) void k_recur(
    const float* __restrict__ gi_f, const float* __restrict__ gi_b,
    const float* __restrict__ Wf_hh, const float* __restrict__ bf_hh,
    const float* __restrict__ Wb_hh, const float* __restrict__ bb_hh,
    const float* __restrict__ h0,
    float* __restrict__ fwd, float* __restrict__ bwd)
{
    const int dir = blockIdx.x;           // 0 = forward, 1 = backward
    const float* gi  = dir ? gi_b  : gi_f;
    const float* Whh = dir ? Wb_hh : Wf_hh;
    const float* bhh = dir ? bb_hh : bf_hh;
    float* outs      = dir ? bwd   : fwd;

    const int tid  = threadIdx.x;
    const int lane = tid & 63;
    const int wv   = tid >> 6;                              // 0..7
    const int kc   = (lane & 3) | ((lane >> 1) & 4);        // bits 0,1,3 -> 0..7
    const int g    = ((lane >> 2) & 1) | ((lane >> 3) & 6); // bits 2,4,5 -> 0..7
    const int u2   = wv * 8 + g;                            // 0..63
    const int ua   = 2 * u2;                                // even unit

    // --- weight fragments -> pinned scalar VGPRs.
    // Slot m4 of this thread holds float4 column (kc*4 + ((m4+kc)&3)) — the
    // same rotated index the h-reads use, so dot pairs match and the 8 kc
    // lanes hit disjoint banks (only kc<->kc+4 alias = free 2-way).
    float W[6][16];
    {
        const float4* Wp = (const float4*)Whh;
#pragma unroll
        for (int rr = 0; rr < 6; ++rr) {
            const int row = (rr >> 1) * HID + ua + (rr & 1);
#pragma unroll
            for (int m4 = 0; m4 < 4; ++m4) {
                const int col4 = kc * 4 + ((m4 + kc) & 3);
                const float4 wv4 = Wp[row * 32 + col4];
                W[rr][m4 * 4 + 0] = wv4.x; W[rr][m4 * 4 + 1] = wv4.y;
                W[rr][m4 * 4 + 2] = wv4.z; W[rr][m4 * 4 + 3] = wv4.w;
            }
        }
#pragma unroll
        for (int rr = 0; rr < 6; ++rr)
#pragma unroll
            for (int m = 0; m < 16; ++m) KEEPF(W[rr][m]);
    }

    float b_ra = bhh[ua],           b_rb = bhh[ua + 1];
    float b_za = bhh[HID + ua],     b_zb = bhh[HID + ua + 1];
    float b_na = bhh[2 * HID + ua], b_nb = bhh[2 * HID + ua + 1];
    KEEPF(b_ra); KEEPF(b_rb); KEEPF(b_za); KEEPF(b_zb); KEEPF(b_na); KEEPF(b_nb);

    const int ginc = dir ? -G3 : G3;
    const int oinc = dir ? -HID : HID;
    const int t0   = dir ? (SEQ - 1) : 0;
    const float* gp = gi + (size_t)t0 * G3 + ua;
    float* op       = outs + (size_t)t0 * HID + ua;

    const float2 h2 = *(const float2*)(h0 + (size_t)dir * BATCH * HID + BSEL * HID + ua);
    float h_a = h2.x, h_b = h2.y;

    float gc0, gc1, gc2, gc3, gc4, gc5;   // current-step gi (+folded bhh for r,z)
    {
        const float2 r2 = *(const float2*)gp;
        const float2 z2 = *(const float2*)(gp + 128);
        const float2 n2 = *(const float2*)(gp + 256);
        gc0 = r2.x + b_ra; gc1 = r2.y + b_rb;
        gc2 = z2.x + b_za; gc3 = z2.y + b_zb;
        gc4 = n2.x;        gc5 = n2.y;
    }

    __shared__ __align__(16) float h_lds[2][HID];
    if (tid < HID) h_lds[0][tid] = h0[(size_t)dir * BATCH * HID + BSEL * HID + tid];
    __syncthreads();

    auto body = [&](int cur) {
        // prefetch next step's gi (address always lands inside the workspace:
        // dir=0 overruns into gi_b's first row, dir=1 into gi_f's last row —
        // both valid memory; values discarded on the final step)
        const float* gpn = gp + ginc;
        const float2 r2 = *(const float2*)gpn;
        const float2 z2 = *(const float2*)(gpn + 128);
        const float2 n2 = *(const float2*)(gpn + 256);

        // partial dots over 16 cols for 6 rows (bank-rotated reads)
        const float4* h4 = (const float4*)(h_lds[cur]);
        float a0 = 0.f, a1 = 0.f, a2 = 0.f, a3 = 0.f, a4 = 0.f, a5 = 0.f;
#pragma unroll
        for (int m4 = 0; m4 < 4; ++m4) {
            const float4 hv = h4[kc * 4 + ((m4 + kc) & 3)];
#define DOT4(acc, rr) \
            acc = fmaf(W[rr][m4*4+0], hv.x, acc); acc = fmaf(W[rr][m4*4+1], hv.y, acc); \
            acc = fmaf(W[rr][m4*4+2], hv.z, acc); acc = fmaf(W[rr][m4*4+3], hv.w, acc)
            DOT4(a0, 0); DOT4(a1, 1); DOT4(a2, 2);
            DOT4(a3, 3); DOT4(a4, 4); DOT4(a5, 5);
#undef DOT4
        }
        // allreduce over the 8 kc lanes (bits 0,1,3) — pure VALU DPP
        a0 = dpp_add<0x128>(dpp_add<0x4E>(dpp_add<0xB1>(a0)));
        a1 = dpp_add<0x128>(dpp_add<0x4E>(dpp_add<0xB1>(a1)));
        a2 = dpp_add<0x128>(dpp_add<0x4E>(dpp_add<0xB1>(a2)));
        a3 = dpp_add<0x128>(dpp_add<0x4E>(dpp_add<0xB1>(a3)));
        a4 = dpp_add<0x128>(dpp_add<0x4E>(dpp_add<0xB1>(a4)));
        a5 = dpp_add<0x128>(dpp_add<0x4E>(dpp_add<0xB1>(a5)));

        // gates (all lanes redundantly — identical fp trajectories)
        const float ra = __builtin_amdgcn_rcpf(1.f + __expf(-(gc0 + a0)));
        const float rb = __builtin_amdgcn_rcpf(1.f + __expf(-(gc1 + a1)));
        const float za = __builtin_amdgcn_rcpf(1.f + __expf(-(gc2 + a2)));
        const float zb = __builtin_amdgcn_rcpf(1.f + __expf(-(gc3 + a3)));
        float ta = gc4 + ra * (a4 + b_na); ta = fminf(fmaxf(ta, -15.f), 15.f);
        float tb = gc5 + rb * (a5 + b_nb); tb = fminf(fmaxf(tb, -15.f), 15.f);
        const float ea = __expf(-2.f * ta), eb = __expf(-2.f * tb);
        const float na = (1.f - ea) * __builtin_amdgcn_rcpf(1.f + ea);
        const float nb = (1.f - eb) * __builtin_amdgcn_rcpf(1.f + eb);
        h_a = (1.f - za) * na + za * h_a;
        h_b = (1.f - zb) * nb + zb * h_b;

        if (kc == 0) {
            ((float2*)(h_lds[cur ^ 1]))[u2] = float2{h_a, h_b};
            *(float2*)op = float2{h_a, h_b};
        }
        gc0 = r2.x + b_ra; gc1 = r2.y + b_rb;
        gc2 = z2.x + b_za; gc3 = z2.y + b_zb;
        gc4 = n2.x;        gc5 = n2.y;
        gp = gpn; op += oinc;
        __syncthreads();
    };

    for (int step = 0; step < SEQ; step += 2) { body(0); body(1); }
}

// ---------------------------------------------------------------------------
// Kernel 3: logits + softmax -> LDS; serial Viterbi forward with batched
// ds_bpermute allgather + fmax tree / equality first-argmax (exact);
// chunked backtrack. One block, 384 threads.
// ---------------------------------------------------------------------------
__global__ __launch_bounds__(G3) void k_out_viterbi(
    const float* __restrict__ fwd, const float* __restrict__ bwd,
    const float* __restrict__ W_out, const float* __restrict__ b_out,
    const float* __restrict__ trans, float* __restrict__ out)
{
    __shared__ float p_lds[(SEQ + 1) * NS];           // +1 pad row for prefetch
    __shared__ unsigned char bp_lds[(SEQ - 1) * NS];
    __shared__ unsigned char cmap[32 * NS];
    __shared__ int bstate[32];
    __shared__ int s_last;

    const int tid = threadIdx.x;

    // ---- Phase A: logits + softmax per timestep ----
    for (int t = tid; t < SEQ; t += G3) {
        const float4* f4 = (const float4*)(fwd + (size_t)t * HID);
        const float4* b4 = (const float4*)(bwd + (size_t)t * HID);
        float lg[NS];
#pragma unroll
        for (int s = 0; s < NS; ++s) lg[s] = b_out[s];
#pragma unroll 4
        for (int k4 = 0; k4 < 32; ++k4) {
            const float4 fv = f4[k4];
            const float4 bv = b4[k4];
#pragma unroll
            for (int s = 0; s < NS; ++s) {
                const float4 wf = ((const float4*)(W_out + s * 256))[k4];
                const float4 wb = ((const float4*)(W_out + s * 256 + HID))[k4];
                lg[s] += wf.x * fv.x + wf.y * fv.y + wf.z * fv.z + wf.w * fv.w
                       + wb.x * bv.x + wb.y * bv.y + wb.z * bv.z + wb.w * bv.w;
            }
        }
        float m = lg[0];
#pragma unroll
        for (int s = 1; s < NS; ++s) m = fmaxf(m, lg[s]);
        float sum = 0.f;
#pragma unroll
        for (int s = 0; s < NS; ++s) { lg[s] = __expf(lg[s] - m); sum += lg[s]; }
        const float inv = 1.f / sum;
#pragma unroll
        for (int s = 0; s < NS; ++s) p_lds[t * NS + s] = lg[s] * inv;
    }
    __syncthreads();

    // ---- Phase B: exact serial Viterbi forward (wave 0, lanes 0..5) ----
    if (tid < 64) {
        const int j = tid;
        const bool act = (j < NS);
        const int jc = act ? j : 0;            // clamped index for LDS prefetch
        float tc0 = act ? trans[0 * NS + j] : 0.f;
        float tc1 = act ? trans[1 * NS + j] : 0.f;
        float tc2 = act ? trans[2 * NS + j] : 0.f;
        float tc3 = act ? trans[3 * NS + j] : 0.f;
        float tc4 = act ? trans[4 * NS + j] : 0.f;
        float tc5 = act ? trans[5 * NS + j] : 0.f;
        float tr = act ? p_lds[j] : -3.0e38f;
        float pv = p_lds[NS + jc];             // prob for t=1

        for (int t = 1; t < SEQ; ++t) {
            // batched allgather of tr (6 bpermutes, single wait)
            const float v0 = bperm_f(0, tr) + tc0;
            const float v1 = bperm_f(1, tr) + tc1;
            const float v2 = bperm_f(2, tr) + tc2;
            const float v3 = bperm_f(3, tr) + tc3;
            const float v4 = bperm_f(4, tr) + tc4;
            const float v5 = bperm_f(5, tr) + tc5;
            const float pnext = p_lds[(t + 1) * NS + jc];  // pad row at t=SEQ-1
            // exact max tree on the critical path
            const float best = fmaxf(fmaxf(fmaxf(v0, v1), v2),
                                     fmaxf(fmaxf(v3, v4), v5));
            const float trn = pv + best;
            // first-argmax via equality (off critical path) == jnp.argmax
            int bi = 5;
            bi = (v4 == best) ? 4 : bi;
            bi = (v3 == best) ? 3 : bi;
            bi = (v2 == best) ? 2 : bi;
            bi = (v1 == best) ? 1 : bi;
            bi = (v0 == best) ? 0 : bi;
            if (act) bp_lds[(t - 1) * NS + j] = (unsigned char)bi;
            tr = act ? trn : tr;
            pv = pnext;
        }
        // final argmax over the 6 trellis values
        const float f0 = bperm_f(0, tr);
        const float f1 = bperm_f(1, tr);
        const float f2 = bperm_f(2, tr);
        const float f3 = bperm_f(3, tr);
        const float f4 = bperm_f(4, tr);
        const float f5 = bperm_f(5, tr);
        const float best = fmaxf(fmaxf(fmaxf(f0, f1), f2),
                                 fmaxf(fmaxf(f3, f4), f5));
        int bi = 5;
        bi = (f4 == best) ? 4 : bi;
        bi = (f3 == best) ? 3 : bi;
        bi = (f2 == best) ? 2 : bi;
        bi = (f1 == best) ? 1 : bi;
        bi = (f0 == best) ? 0 : bi;
        if (tid == 0) { out[0] = best; s_last = bi; }
    }
    __syncthreads();

    // ---- Phase C1: per-chunk backpointer composition (192 walkers) ----
    if (tid < 32 * NS) {
        const int c = tid / NS, s0 = tid % NS;
        const int hi = (c == 31) ? (SEQ - 1) : 64 * (c + 1);
        const int lo = 64 * c;
        int s = s0;
        for (int tau = hi; tau > lo; --tau) s = bp_lds[(tau - 1) * NS + s];
        cmap[c * NS + s0] = (unsigned char)s;
    }
    __syncthreads();

    // ---- Phase C2: serial splice over 32 chunk boundaries ----
    if (tid == 0) {
        int s = s_last;
        for (int c = 31; c >= 0; --c) {
            s = cmap[c * NS + s];
            bstate[c] = s;
        }
    }
    __syncthreads();

    // ---- Phase C3: parallel emit (32 chunks re-walk) ----
    if (tid < 32) {
        const int c = tid;
        const int hi = (c == 31) ? (SEQ - 1) : 64 * (c + 1);
        const int lo = 64 * c;
        int s = (c == 31) ? s_last : bstate[c + 1];
        for (int tau = hi; tau > lo; --tau) {
            out[1 + tau] = (float)s;
            s = bp_lds[(tau - 1) * NS + s];
        }
        if (c == 0) out[1] = (float)s;   // time 0
    }
}

// ---------------------------------------------------------------------------
extern "C" void kernel_launch(void* const* d_in, const int* in_sizes, int n_in,
                              void* d_out, int out_size, void* d_ws, size_t ws_size,
                              hipStream_t stream)
{
    (void)in_sizes; (void)n_in; (void)out_size; (void)ws_size;

    const int*   sent  = (const int*)  d_in[0];
    const float* emb   = (const float*)d_in[1];
    const float* h0    = (const float*)d_in[2];
    const float* Wf_ih = (const float*)d_in[3];
    const float* Wf_hh = (const float*)d_in[4];
    const float* bf_ih = (const float*)d_in[5];
    const float* bf_hh = (const float*)d_in[6];
    const float* Wb_ih = (const float*)d_in[7];
    const float* Wb_hh = (const float*)d_in[8];
    const float* bb_ih = (const float*)d_in[9];
    const float* bb_hh = (const float*)d_in[10];
    const float* W_out = (const float*)d_in[11];
    const float* b_out = (const float*)d_in[12];
    const float* trans = (const float*)d_in[13];
    float* out = (float*)d_out;

    // workspace layout (floats): gi_f[SEQ*G3] | gi_b[SEQ*G3] | fwd[SEQ*HID] | bwd[SEQ*HID]
    float* ws   = (float*)d_ws;
    float* gi_f = ws;
    float* gi_b = ws + (size_t)SEQ * G3;
    float* fwdb = ws + (size_t)2 * SEQ * G3;
    float* bwdb = fwdb + (size_t)SEQ * HID;

    k_input_proj<<<SEQ / 4, G3, 0, stream>>>(sent, emb, Wf_ih, bf_ih, Wb_ih, bb_ih, gi_f, gi_b);
    k_recur<<<2, 512, 0, stream>>>(gi_f, gi_b, Wf_hh, bf_hh, Wb_hh, bb_hh, h0, fwdb, bwdb);
    k_out_viterbi<<<1, G3, 0, stream>>>(fwdb, bwdb, W_out, b_out, trans, out);
}

// Round 6
// 1610.282 us; speedup vs baseline: 1.9529x; 1.2005x over previous
//
#include <hip/hip_runtime.h>
#include <math.h>
#include <stdint.h>

// Problem constants (from reference setup_inputs)
constexpr int SEQ   = 2048;  // T
constexpr int BATCH = 64;    // B
constexpr int EMB   = 100;   // E
constexpr int HID   = 128;   // H
constexpr int G3    = 384;   // 3*H
constexpr int NS    = 6;     // S (CRF states)
constexpr int BSEL  = 63;    // only batch row 63 affects the output

// Opaque register pin on a 32-bit value (single VGPR).
#define KEEPI(v) asm volatile("" : "+v"(v))

typedef _Float16 h2 __attribute__((ext_vector_type(2)));

// Packed f16 dot2 with fp32 accumulate. v_dot2_f32_f16 products are exact in
// f32 (11x11-bit mantissas), only the input casts round (~5e-4 rel).
#if defined(__has_builtin)
#if __has_builtin(__builtin_amdgcn_fdot2)
#define HAVE_FDOT2 1
#endif
#endif

__device__ __forceinline__ float dot2(uint32_t w, uint32_t h, float acc) {
#ifdef HAVE_FDOT2
    return __builtin_amdgcn_fdot2(__builtin_bit_cast(h2, w),
                                  __builtin_bit_cast(h2, h), acc, false);
#else
    h2 wv = __builtin_bit_cast(h2, w), hv = __builtin_bit_cast(h2, h);
    acc = fmaf((float)wv.x, (float)hv.x, acc);
    return fmaf((float)wv.y, (float)hv.y, acc);
#endif
}

__device__ __forceinline__ uint32_t pack_f16(float a, float b) {
    h2 p; p.x = (_Float16)a; p.y = (_Float16)b;
    return __builtin_bit_cast(uint32_t, p);
}

// DPP cross-lane adds (VALU pipe, no LDS)
// xor1 = quad_perm(1,0,3,2)=0xB1, xor2 = quad_perm(2,3,0,1)=0x4E,
// xor8 = row_ror:8 = 0x128
template <int CTRL>
__device__ __forceinline__ float dpp_add(float x) {
    int v = __builtin_amdgcn_update_dpp(0, __float_as_int(x), CTRL, 0xF, 0xF, true);
    return x + __int_as_float(v);
}

__device__ __forceinline__ float bperm_f(int srclane, float x) {
    return __int_as_float(__builtin_amdgcn_ds_bpermute(srclane * 4, __float_as_int(x)));
}

// ---------------------------------------------------------------------------
// Kernel 1: embedding lookup + input projection for batch row 63 only.
// 4 timesteps per block; weight rows register-cached across the 4 t's.
// (unchanged — attribution)
// ---------------------------------------------------------------------------
__global__ __launch_bounds__(G3) void k_input_proj(
    const int* __restrict__ sent, const float* __restrict__ emb,
    const float* __restrict__ Wf_ih, const float* __restrict__ bf_ih,
    const float* __restrict__ Wb_ih, const float* __restrict__ bb_ih,
    float* __restrict__ gi_f, float* __restrict__ gi_b)
{
    const int tb = blockIdx.x * 4;
    const int j  = threadIdx.x;           // 0..383
    __shared__ __align__(16) float x_s[4][EMB];

    int toks[4];
#pragma unroll
    for (int tt = 0; tt < 4; ++tt) toks[tt] = sent[BSEL * SEQ + tb + tt];
    if (j < EMB) {
#pragma unroll
        for (int tt = 0; tt < 4; ++tt)
            x_s[tt][j] = emb[(size_t)toks[tt] * EMB + j];
    }
    __syncthreads();

    float4 wf4[25], wb4[25];
    const float4* wfp = (const float4*)(Wf_ih + (size_t)j * EMB);
    const float4* wbp = (const float4*)(Wb_ih + (size_t)j * EMB);
#pragma unroll
    for (int m = 0; m < 25; ++m) { wf4[m] = wfp[m]; wb4[m] = wbp[m]; }
    const float bf = bf_ih[j], bb = bb_ih[j];

#pragma unroll
    for (int tt = 0; tt < 4; ++tt) {
        const float4* xs = (const float4*)(x_s[tt]);
        float af = 0.f, ab = 0.f;
#pragma unroll
        for (int m = 0; m < 25; ++m) {
            const float4 xv = xs[m];
            af = fmaf(wf4[m].x, xv.x, af); af = fmaf(wf4[m].y, xv.y, af);
            af = fmaf(wf4[m].z, xv.z, af); af = fmaf(wf4[m].w, xv.w, af);
            ab = fmaf(wb4[m].x, xv.x, ab); ab = fmaf(wb4[m].y, xv.y, ab);
            ab = fmaf(wb4[m].z, xv.z, ab); ab = fmaf(wb4[m].w, xv.w, ab);
        }
        gi_f[(tb + tt) * G3 + j] = af + bf;
        gi_b[(tb + tt) * G3 + j] = ab + bb;
    }
}

// ---------------------------------------------------------------------------
// Kernel 2: sequential GRU recurrence, one block (512 thr) per direction.
// Thread = (u2 = unit-pair 0..63, kc = 16-col chunk 0..7).
//   kc on lane bits {0,1,3}; unit-group on bits {2,4,5} (+ wave id).
// Weights as 48 packed-f16 uints/thread (2x fewer regs + 2x fewer MACs via
// v_dot2_f32_f16, fp32 accumulate). h stored in LDS as f16 pairs: 2
// ds_read_b128/thread/step (2-way broadcast alias only = free). h_old for
// the z-blend stays fp32 in registers. 3-stage DPP allreduce; one barrier
// per step (double-buffered h).
// ---------------------------------------------------------------------------
__global__ __launch_bounds__(512, 1) void k_recur(
    const float* __restrict__ gi_f, const float* __restrict__ gi_b,
    const float* __restrict__ Wf_hh, const float* __restrict__ bf_hh,
    const float* __restrict__ Wb_hh, const float* __restrict__ bb_hh,
    const float* __restrict__ h0,
    float* __restrict__ fwd, float* __restrict__ bwd)
{
    const int dir = blockIdx.x;           // 0 = forward, 1 = backward
    const float* gi  = dir ? gi_b  : gi_f;
    const float* Whh = dir ? Wb_hh : Wf_hh;
    const float* bhh = dir ? bb_hh : bf_hh;
    float* outs      = dir ? bwd   : fwd;

    const int tid  = threadIdx.x;
    const int lane = tid & 63;
    const int wv   = tid >> 6;                              // 0..7
    const int kc   = (lane & 3) | ((lane >> 1) & 4);        // bits 0,1,3 -> 0..7
    const int g    = ((lane >> 2) & 1) | ((lane >> 3) & 6); // bits 2,4,5 -> 0..7
    const int u2   = wv * 8 + g;                            // 0..63
    const int ua   = 2 * u2;                                // even unit

    // --- weight fragments -> 48 packed f16 pairs, pinned.
    // Row rr covers cols [16kc, 16kc+16): slots i=0..7 hold cols 16kc+2i,+2i+1.
    uint32_t Wp[6][8];
    {
        const float4* WpF = (const float4*)Whh;
#pragma unroll
        for (int rr = 0; rr < 6; ++rr) {
            const int row = (rr >> 1) * HID + ua + (rr & 1);
#pragma unroll
            for (int q = 0; q < 4; ++q) {
                const float4 w4 = WpF[row * 32 + kc * 4 + q];
                Wp[rr][2 * q]     = pack_f16(w4.x, w4.y);
                Wp[rr][2 * q + 1] = pack_f16(w4.z, w4.w);
            }
        }
#pragma unroll
        for (int rr = 0; rr < 6; ++rr)
#pragma unroll
            for (int m = 0; m < 8; ++m) KEEPI(Wp[rr][m]);
    }

    const float b_ra = bhh[ua],           b_rb = bhh[ua + 1];
    const float b_za = bhh[HID + ua],     b_zb = bhh[HID + ua + 1];
    const float b_na = bhh[2 * HID + ua], b_nb = bhh[2 * HID + ua + 1];

    const int ginc = dir ? -G3 : G3;
    const int oinc = dir ? -HID : HID;
    const int t0   = dir ? (SEQ - 1) : 0;
    const float* gp = gi + (size_t)t0 * G3 + ua;
    float* op       = outs + (size_t)t0 * HID + ua;

    const float2 h2i = *(const float2*)(h0 + (size_t)dir * BATCH * HID + BSEL * HID + ua);
    float h_a = h2i.x, h_b = h2i.y;

    float gc0, gc1, gc2, gc3, gc4, gc5;   // current-step gi (+folded bhh for r,z)
    {
        const float2 r2 = *(const float2*)gp;
        const float2 z2 = *(const float2*)(gp + 128);
        const float2 n2 = *(const float2*)(gp + 256);
        gc0 = r2.x + b_ra; gc1 = r2.y + b_rb;
        gc2 = z2.x + b_za; gc3 = z2.y + b_zb;
        gc4 = n2.x;        gc5 = n2.y;
    }

    // h as packed f16 pairs: h_lds[buf][u2] = {h[2u2], h[2u2+1]}
    __shared__ __align__(16) uint32_t h_lds[2][HID / 2];
    if (tid < HID / 2) {
        const float2 hh = *(const float2*)(h0 + (size_t)dir * BATCH * HID + BSEL * HID + 2 * tid);
        h_lds[0][tid] = pack_f16(hh.x, hh.y);
    }
    __syncthreads();

    auto body = [&](int cur) {
        // prefetch next step's gi (overrun on final step lands in the
        // adjacent gi buffer — valid memory, value discarded)
        const float* gpn = gp + ginc;
        const float2 r2 = *(const float2*)gpn;
        const float2 z2 = *(const float2*)(gpn + 128);
        const float2 n2 = *(const float2*)(gpn + 256);

        // this thread's 16 h values (8 packed pairs) = 2 ds_read_b128
        const uint4* h16 = (const uint4*)(h_lds[cur]);
        const uint4 q0 = h16[2 * kc];
        const uint4 q1 = h16[2 * kc + 1];
        const uint32_t hw0 = q0.x, hw1 = q0.y, hw2 = q0.z, hw3 = q0.w;
        const uint32_t hw4 = q1.x, hw5 = q1.y, hw6 = q1.z, hw7 = q1.w;

        float a0 = 0.f, a1 = 0.f, a2 = 0.f, a3 = 0.f, a4 = 0.f, a5 = 0.f;
#define DOTSTEP(i, hwv) \
        a0 = dot2(Wp[0][i], hwv, a0); a1 = dot2(Wp[1][i], hwv, a1); \
        a2 = dot2(Wp[2][i], hwv, a2); a3 = dot2(Wp[3][i], hwv, a3); \
        a4 = dot2(Wp[4][i], hwv, a4); a5 = dot2(Wp[5][i], hwv, a5)
        DOTSTEP(0, hw0); DOTSTEP(1, hw1); DOTSTEP(2, hw2); DOTSTEP(3, hw3);
        DOTSTEP(4, hw4); DOTSTEP(5, hw5); DOTSTEP(6, hw6); DOTSTEP(7, hw7);
#undef DOTSTEP

        // allreduce over the 8 kc lanes (bits 0,1,3) — pure VALU DPP
        a0 = dpp_add<0x128>(dpp_add<0x4E>(dpp_add<0xB1>(a0)));
        a1 = dpp_add<0x128>(dpp_add<0x4E>(dpp_add<0xB1>(a1)));
        a2 = dpp_add<0x128>(dpp_add<0x4E>(dpp_add<0xB1>(a2)));
        a3 = dpp_add<0x128>(dpp_add<0x4E>(dpp_add<0xB1>(a3)));
        a4 = dpp_add<0x128>(dpp_add<0x4E>(dpp_add<0xB1>(a4)));
        a5 = dpp_add<0x128>(dpp_add<0x4E>(dpp_add<0xB1>(a5)));

        // gates (all lanes redundantly — identical fp trajectories)
        const float ra = __builtin_amdgcn_rcpf(1.f + __expf(-(gc0 + a0)));
        const float rb = __builtin_amdgcn_rcpf(1.f + __expf(-(gc1 + a1)));
        const float za = __builtin_amdgcn_rcpf(1.f + __expf(-(gc2 + a2)));
        const float zb = __builtin_amdgcn_rcpf(1.f + __expf(-(gc3 + a3)));
        float ta = gc4 + ra * (a4 + b_na); ta = fminf(fmaxf(ta, -15.f), 15.f);
        float tb = gc5 + rb * (a5 + b_nb); tb = fminf(fmaxf(tb, -15.f), 15.f);
        const float ea = __expf(-2.f * ta), eb = __expf(-2.f * tb);
        const float na = (1.f - ea) * __builtin_amdgcn_rcpf(1.f + ea);
        const float nb = (1.f - eb) * __builtin_amdgcn_rcpf(1.f + eb);
        h_a = (1.f - za) * na + za * h_a;
        h_b = (1.f - zb) * nb + zb * h_b;

        if (kc == 0) {
            h_lds[cur ^ 1][u2] = pack_f16(h_a, h_b);
            *(float2*)op = float2{h_a, h_b};
        }
        gc0 = r2.x + b_ra; gc1 = r2.y + b_rb;
        gc2 = z2.x + b_za; gc3 = z2.y + b_zb;
        gc4 = n2.x;        gc5 = n2.y;
        gp = gpn; op += oinc;
        __syncthreads();
    };

    for (int step = 0; step < SEQ; step += 2) { body(0); body(1); }
}

// ---------------------------------------------------------------------------
// Kernel 3: logits + softmax -> LDS; serial Viterbi forward with batched
// ds_bpermute allgather + fmax tree / equality first-argmax (exact);
// chunked backtrack. One block, 384 threads. (unchanged — attribution)
// ---------------------------------------------------------------------------
__global__ __launch_bounds__(G3) void k_out_viterbi(
    const float* __restrict__ fwd, const float* __restrict__ bwd,
    const float* __restrict__ W_out, const float* __restrict__ b_out,
    const float* __restrict__ trans, float* __restrict__ out)
{
    __shared__ float p_lds[(SEQ + 1) * NS];           // +1 pad row for prefetch
    __shared__ unsigned char bp_lds[(SEQ - 1) * NS];
    __shared__ unsigned char cmap[32 * NS];
    __shared__ int bstate[32];
    __shared__ int s_last;

    const int tid = threadIdx.x;

    // ---- Phase A: logits + softmax per timestep ----
    for (int t = tid; t < SEQ; t += G3) {
        const float4* f4 = (const float4*)(fwd + (size_t)t * HID);
        const float4* b4 = (const float4*)(bwd + (size_t)t * HID);
        float lg[NS];
#pragma unroll
        for (int s = 0; s < NS; ++s) lg[s] = b_out[s];
#pragma unroll 4
        for (int k4 = 0; k4 < 32; ++k4) {
            const float4 fv = f4[k4];
            const float4 bv = b4[k4];
#pragma unroll
            for (int s = 0; s < NS; ++s) {
                const float4 wf = ((const float4*)(W_out + s * 256))[k4];
                const float4 wb = ((const float4*)(W_out + s * 256 + HID))[k4];
                lg[s] += wf.x * fv.x + wf.y * fv.y + wf.z * fv.z + wf.w * fv.w
                       + wb.x * bv.x + wb.y * bv.y + wb.z * bv.z + wb.w * bv.w;
            }
        }
        float m = lg[0];
#pragma unroll
        for (int s = 1; s < NS; ++s) m = fmaxf(m, lg[s]);
        float sum = 0.f;
#pragma unroll
        for (int s = 0; s < NS; ++s) { lg[s] = __expf(lg[s] - m); sum += lg[s]; }
        const float inv = 1.f / sum;
#pragma unroll
        for (int s = 0; s < NS; ++s) p_lds[t * NS + s] = lg[s] * inv;
    }
    __syncthreads();

    // ---- Phase B: exact serial Viterbi forward (wave 0, lanes 0..5) ----
    if (tid < 64) {
        const int j = tid;
        const bool act = (j < NS);
        const int jc = act ? j : 0;            // clamped index for LDS prefetch
        float tc0 = act ? trans[0 * NS + j] : 0.f;
        float tc1 = act ? trans[1 * NS + j] : 0.f;
        float tc2 = act ? trans[2 * NS + j] : 0.f;
        float tc3 = act ? trans[3 * NS + j] : 0.f;
        float tc4 = act ? trans[4 * NS + j] : 0.f;
        float tc5 = act ? trans[5 * NS + j] : 0.f;
        float tr = act ? p_lds[j] : -3.0e38f;
        float pv = p_lds[NS + jc];             // prob for t=1

        for (int t = 1; t < SEQ; ++t) {
            const float v0 = bperm_f(0, tr) + tc0;
            const float v1 = bperm_f(1, tr) + tc1;
            const float v2 = bperm_f(2, tr) + tc2;
            const float v3 = bperm_f(3, tr) + tc3;
            const float v4 = bperm_f(4, tr) + tc4;
            const float v5 = bperm_f(5, tr) + tc5;
            const float pnext = p_lds[(t + 1) * NS + jc];  // pad row at t=SEQ-1
            const float best = fmaxf(fmaxf(fmaxf(v0, v1), v2),
                                     fmaxf(fmaxf(v3, v4), v5));
            const float trn = pv + best;
            int bi = 5;
            bi = (v4 == best) ? 4 : bi;
            bi = (v3 == best) ? 3 : bi;
            bi = (v2 == best) ? 2 : bi;
            bi = (v1 == best) ? 1 : bi;
            bi = (v0 == best) ? 0 : bi;
            if (act) bp_lds[(t - 1) * NS + j] = (unsigned char)bi;
            tr = act ? trn : tr;
            pv = pnext;
        }
        const float f0 = bperm_f(0, tr);
        const float f1 = bperm_f(1, tr);
        const float f2 = bperm_f(2, tr);
        const float f3 = bperm_f(3, tr);
        const float f4 = bperm_f(4, tr);
        const float f5 = bperm_f(5, tr);
        const float best = fmaxf(fmaxf(fmaxf(f0, f1), f2),
                                 fmaxf(fmaxf(f3, f4), f5));
        int bi = 5;
        bi = (f4 == best) ? 4 : bi;
        bi = (f3 == best) ? 3 : bi;
        bi = (f2 == best) ? 2 : bi;
        bi = (f1 == best) ? 1 : bi;
        bi = (f0 == best) ? 0 : bi;
        if (tid == 0) { out[0] = best; s_last = bi; }
    }
    __syncthreads();

    // ---- Phase C1: per-chunk backpointer composition (192 walkers) ----
    if (tid < 32 * NS) {
        const int c = tid / NS, s0 = tid % NS;
        const int hi = (c == 31) ? (SEQ - 1) : 64 * (c + 1);
        const int lo = 64 * c;
        int s = s0;
        for (int tau = hi; tau > lo; --tau) s = bp_lds[(tau - 1) * NS + s];
        cmap[c * NS + s0] = (unsigned char)s;
    }
    __syncthreads();

    // ---- Phase C2: serial splice over 32 chunk boundaries ----
    if (tid == 0) {
        int s = s_last;
        for (int c = 31; c >= 0; --c) {
            s = cmap[c * NS + s];
            bstate[c] = s;
        }
    }
    __syncthreads();

    // ---- Phase C3: parallel emit (32 chunks re-walk) ----
    if (tid < 32) {
        const int c = tid;
        const int hi = (c == 31) ? (SEQ - 1) : 64 * (c + 1);
        const int lo = 64 * c;
        int s = (c == 31) ? s_last : bstate[c + 1];
        for (int tau = hi; tau > lo; --tau) {
            out[1 + tau] = (float)s;
            s = bp_lds[(tau - 1) * NS + s];
        }
        if (c == 0) out[1] = (float)s;   // time 0
    }
}

// ---------------------------------------------------------------------------
extern "C" void kernel_launch(void* const* d_in, const int* in_sizes, int n_in,
                              void* d_out, int out_size, void* d_ws, size_t ws_size,
                              hipStream_t stream)
{
    (void)in_sizes; (void)n_in; (void)out_size; (void)ws_size;

    const int*   sent  = (const int*)  d_in[0];
    const float* emb   = (const float*)d_in[1];
    const float* h0    = (const float*)d_in[2];
    const float* Wf_ih = (const float*)d_in[3];
    const float* Wf_hh = (const float*)d_in[4];
    const float* bf_ih = (const float*)d_in[5];
    const float* bf_hh = (const float*)d_in[6];
    const float* Wb_ih = (const float*)d_in[7];
    const float* Wb_hh = (const float*)d_in[8];
    const float* bb_ih = (const float*)d_in[9];
    const float* bb_hh = (const float*)d_in[10];
    const float* W_out = (const float*)d_in[11];
    const float* b_out = (const float*)d_in[12];
    const float* trans = (const float*)d_in[13];
    float* out = (float*)d_out;

    // workspace layout (floats): gi_f[SEQ*G3] | gi_b[SEQ*G3] | fwd[SEQ*HID] | bwd[SEQ*HID]
    float* ws   = (float*)d_ws;
    float* gi_f = ws;
    float* gi_b = ws + (size_t)SEQ * G3;
    float* fwdb = ws + (size_t)2 * SEQ * G3;
    float* bwdb = fwdb + (size_t)SEQ * HID;

    k_input_proj<<<SEQ / 4, G3, 0, stream>>>(sent, emb, Wf_ih, bf_ih, Wb_ih, bb_ih, gi_f, gi_b);
    k_recur<<<2, 512, 0, stream>>>(gi_f, gi_b, Wf_hh, bf_hh, Wb_hh, bb_hh, h0, fwdb, bwdb);
    k_out_viterbi<<<1, G3, 0, stream>>>(fwdb, bwdb, W_out, b_out, trans, out);
}